// Round 1
// baseline (462.491 us; speedup 1.0000x reference)
//
#include <hip/hip_runtime.h>
#include <math.h>

#define B_SZ   64
#define N_SAMP 128000
#define FRAME  512
#define HALF   256
#define HOP    256
#define NF     257
#define T_FR   501
#define FP     257      // row stride of power planes (B,T,FP)
#define CHUNK  64
#define WARM   48
#define NCH    8        // ceil(501/64)

#define EPS_F 1.1920928955078125e-07f
#define MPI_D 3.14159265358979323846

// ---------------- Kernel A: STFT power, direct folded DFT ----------------
// grid (T_FR, B_SZ, 2), block 256. Writes power[b][t][f] (coalesced rows).
__global__ __launch_bounds__(256)
void stft_power_kernel(const float* __restrict__ intf,
                       const float* __restrict__ sig,
                       float* __restrict__ outN,   // noise power  (interference)
                       float* __restrict__ outY)   // noisy power (input_sig)
{
    const int t = blockIdx.x;
    const int b = blockIdx.y;
    const int s = blockIdx.z;
    const float* x = (s == 0 ? intf : sig) + (size_t)b * N_SAMP;

    __shared__ float sh[FRAME];
    __shared__ __align__(16) float ge[HALF];   // s[m] + s[m+256]
    __shared__ __align__(16) float go[HALF];   // s[m] - s[m+256]

    const int tid = threadIdx.x;

    // load frame with reflect padding + sqrt-hann window (= sin(pi*n/512))
    for (int k = tid; k < FRAME; k += 256) {
        int pos = t * HOP + k - HALF;
        if (pos < 0) pos = -pos;
        else if (pos >= N_SAMP) pos = 2 * N_SAMP - 2 - pos;
        float w = sinf((float)k * (float)(MPI_D / FRAME));
        sh[k] = x[pos] * w;
    }
    __syncthreads();
    ge[tid] = sh[tid] + sh[tid + HALF];
    go[tid] = sh[tid] - sh[tid + HALF];
    __syncthreads();

    const int f = tid;
    // X[f] = sum_{m<256} g[m] * z^m,  z = e^{-i*pi*f/256},  g = (f even ? ge : go)
    const float4* gv = (const float4*)((f & 1) ? go : ge);

    float thf = -(float)(MPI_D / 256.0) * (float)f;
    float c1, s1v, c4, s4;
    __sincosf(thf, &s1v, &c1);            // fast; rotation error ~1e-5, fine
    __sincosf(4.0f * thf, &s4, &c4);
    // refine with precise versions (cheap, once per thread)
    s1v = sinf(thf);  c1 = cosf(thf);
    s4  = sinf(4.0f * thf); c4 = cosf(4.0f * thf);

    float Zr = 1.f, Zi = 0.f;             // (z^4)^k
    float re0=0,im0=0,re1=0,im1=0,re2=0,im2=0,re3=0,im3=0;
    #pragma unroll 8
    for (int k = 0; k < HALF/4; ++k) {
        float4 g = gv[k];
        re0 = fmaf(g.x, Zr, re0); im0 = fmaf(g.x, Zi, im0);
        re1 = fmaf(g.y, Zr, re1); im1 = fmaf(g.y, Zi, im1);
        re2 = fmaf(g.z, Zr, re2); im2 = fmaf(g.z, Zi, im2);
        re3 = fmaf(g.w, Zr, re3); im3 = fmaf(g.w, Zi, im3);
        float nzr = fmaf(Zr, c4, -Zi * s4);
        float nzi = fmaf(Zi, c4,  Zr * s4);
        Zr = nzr; Zi = nzi;
    }
    // Horner: X = acc0 + z*(acc1 + z*(acc2 + z*acc3))
    float hr = re3, hi = im3, tr;
    tr = fmaf(hr, c1, -hi * s1v); hi = fmaf(hi, c1, hr * s1v); hr = tr;
    hr += re2; hi += im2;
    tr = fmaf(hr, c1, -hi * s1v); hi = fmaf(hi, c1, hr * s1v); hr = tr;
    hr += re1; hi += im1;
    tr = fmaf(hr, c1, -hi * s1v); hi = fmaf(hi, c1, hr * s1v); hr = tr;
    hr += re0; hi += im0;

    float* op = (s == 0) ? outN : outY;
    size_t base = ((size_t)b * T_FR + t) * FP;
    op[base + f] = fmaf(hr, hr, hi * hi);

    if (f == 0) {
        // Nyquist bin 256: sum_n s[n]*(-1)^n = sum_m ge[m]*(-1)^m (im = 0)
        float a0=0,a1=0,a2=0,a3=0;
        for (int m = 0; m < HALF; m += 8) {
            a0 += ge[m]   - ge[m+1];
            a1 += ge[m+2] - ge[m+3];
            a2 += ge[m+4] - ge[m+5];
            a3 += ge[m+6] - ge[m+7];
        }
        float r = (a0 + a1) + (a2 + a3);
        op[base + 256] = r * r;
    }
}

// ------------- Kernel B: chunked IIR scan + SPP + MSE reduction -------------
// thread = (b, chunk, f); f fastest for coalesced power-plane reads.
__global__ __launch_bounds__(256)
void spp_loss_kernel(const float* __restrict__ noiseP,
                     const float* __restrict__ noisyP,
                     const float* __restrict__ est,
                     float* __restrict__ out,
                     float alpha)
{
    const double XI = 31.622776601683793;
    const float RATIO = (float)(1.0 + XI);            // P_H0/P_H1 * (1+xi)
    const float COEF  = (float)(XI / (1.0 + XI));
    const float INVN  = (float)(1.0 / ((double)B_SZ * NF * T_FR));

    int tid = blockIdx.x * blockDim.x + threadIdx.x;
    int f   = tid % NF;
    int rem = tid / NF;
    int c   = rem % NCH;
    int b   = rem / NCH;

    float local = 0.f;
    if (b < B_SZ) {
        int t0   = c * CHUNK;
        int tend = min(T_FR, t0 + CHUNK);
        int ts   = max(0, t0 - WARM);
        const float* nrow = noiseP + (size_t)b * T_FR * FP + f;
        const float* yrow = noisyP + (size_t)b * T_FR * FP + f;
        const float* erow = est + ((size_t)b * NF + f) * T_FR;
        float oma = 1.f - alpha;
        float v = nrow[(size_t)ts * FP];
        if (ts == t0) {   // only chunk 0: emit t=0 (var[0] = p[0])
            float np = yrow[(size_t)ts * FP];
            float expo = -np / (v + EPS_F) * COEF;
            float spp  = 1.f / fmaf(RATIO, expf(expo), 1.f);
            float d = erow[ts] - spp;
            local = fmaf(d, d, local);
        }
        for (int t = ts + 1; t < tend; ++t) {
            v = fmaf(alpha, v, oma * nrow[(size_t)t * FP]);
            if (t >= t0) {
                float np = yrow[(size_t)t * FP];
                float expo = -np / (v + EPS_F) * COEF;
                float spp  = 1.f / fmaf(RATIO, expf(expo), 1.f);
                float d = erow[t] - spp;
                local = fmaf(d, d, local);
            }
        }
    }

    // block reduction: wave shuffle then LDS
    for (int off = 32; off > 0; off >>= 1)
        local += __shfl_down(local, off);
    __shared__ float wsum[4];
    if ((threadIdx.x & 63) == 0) wsum[threadIdx.x >> 6] = local;
    __syncthreads();
    if (threadIdx.x == 0) {
        float ssum = (wsum[0] + wsum[1]) + (wsum[2] + wsum[3]);
        atomicAdd(out, ssum * INVN);
    }
}

extern "C" void kernel_launch(void* const* d_in, const int* in_sizes, int n_in,
                              void* d_out, int out_size, void* d_ws, size_t ws_size,
                              hipStream_t stream) {
    const float* est  = (const float*)d_in[0];   // spp_estimate (B,1,F,T)
    const float* sig  = (const float*)d_in[1];   // input_sig    (B,1,N)
    const float* intf = (const float*)d_in[2];   // interference (B,1,N)

    float* noiseP = (float*)d_ws;                          // (B,T,FP)
    float* noisyP = noiseP + (size_t)B_SZ * T_FR * FP;     // (B,T,FP)

    dim3 gA(T_FR, B_SZ, 2);
    hipLaunchKernelGGL(stft_power_kernel, gA, dim3(256), 0, stream,
                       intf, sig, noiseP, noisyP);

    hipMemsetAsync(d_out, 0, sizeof(float), stream);

    const double alpha_d = exp(-((double)HOP) / (16000.0 * 0.072));
    dim3 gB((B_SZ * NCH * NF + 255) / 256);
    hipLaunchKernelGGL(spp_loss_kernel, gB, dim3(256), 0, stream,
                       noiseP, noisyP, est, (float*)d_out, (float)alpha_d);
}

// Round 2
// 356.905 us; speedup vs baseline: 1.2958x; 1.2958x over previous
//
#include <hip/hip_runtime.h>
#include <hip/hip_bf16.h>
#include <math.h>

typedef __attribute__((ext_vector_type(8))) short bf16x8;
typedef __attribute__((ext_vector_type(4))) float f32x4;
typedef __attribute__((ext_vector_type(8))) unsigned short u16x8;

#define NSAMP  128000
#define TFR    501
#define NFR    32064       // 64*501 frames per signal
#define MTOT   64128       // 2 signals
#define FPOW   257
#define KTOT   512
#define NF     257
#define T_FR   501
#define B_SZ   64
#define CHUNK  64
#define WARM   48
#define NCH    8
#define EPS_F  1.1920928955078125e-07f

// ---------------- basis init: Bt[col][k] = w[k] * {cos,-sin}(2*pi*bin*k/512) ----
// col = (bin>>4)*32 + isIm*16 + (bin&15), bins 0..255; col 16 (dead im of DC)
// holds the Nyquist (bin 256) real basis w[k]*(-1)^k.
__global__ __launch_bounds__(256)
void build_basis(unsigned short* __restrict__ Bt) {
    int col = blockIdx.x;                  // 0..511
    int g = col >> 5, o = col & 15;
    int isIm = (col >> 4) & 1;
    int bin = g * 16 + o;
    for (int k = threadIdx.x; k < 512; k += 256) {
        float w = sinf((float)k * (float)(M_PI / 512.0));   // sqrt-hann
        float v;
        if (col == 16) {
            v = w * ((k & 1) ? -1.f : 1.f);
        } else {
            int mm = (bin * k) & 511;                        // exact phase reduction
            float th = (float)mm * (float)(2.0 * M_PI / 512.0);
            v = w * (isIm ? -sinf(th) : cosf(th));
        }
        __hip_bfloat16 h = __float2bfloat16(v);
        Bt[(size_t)col * KTOT + k] = *reinterpret_cast<unsigned short*>(&h);
    }
}

// ---------------- MFMA DFT GEMM: power[R][bin], R = (s*64+b)*501+t ----------
__global__ __launch_bounds__(256, 2)
void dft_gemm(const float* __restrict__ sig,
              const float* __restrict__ intf,
              const unsigned short* __restrict__ Bt,
              float* __restrict__ powo)
{
    __shared__ unsigned short Al[2][128 * 64];
    __shared__ unsigned short Bl[2][128 * 64];

    const int mt = blockIdx.x;           // 0..500  (M-tile, 128 frames)
    const int nt = blockIdx.y;           // 0..3    (N-tile, 128 cols)
    const int tid = threadIdx.x;
    const int lane = tid & 63, wid = tid >> 6;
    const int wm = wid >> 1, wn = wid & 1;

    // staging assignment: 2 threads per row, 32 elems each
    const int ar = tid >> 1;
    const int ak = (tid & 1) * 32;
    const int mrow = mt * 128 + ar;
    const int sb = mrow / TFR;
    const int tt = mrow - sb * TFR;
    const float* xrow = ((sb >> 6) ? sig : intf) + (size_t)(sb & 63) * NSAMP;
    const int tbase = tt * 256 - 256;
    const bool edge = (tt == 0) || (tt == TFR - 1);
    const unsigned short* brow = Bt + (size_t)(nt * 128 + ar) * KTOT + ak;

    f32x4 acc[4][4];
    #pragma unroll
    for (int i = 0; i < 4; ++i)
        #pragma unroll
        for (int j = 0; j < 4; ++j) acc[i][j] = 0;

    float areg[32];
    u16x8 breg[4];

    auto load_step = [&](int st) {
        int k0 = st * 64 + ak;
        if (!edge) {
            const float4* p = (const float4*)(xrow + tbase + k0);
            #pragma unroll
            for (int c = 0; c < 8; ++c) {
                float4 v = p[c];
                areg[c*4+0] = v.x; areg[c*4+1] = v.y;
                areg[c*4+2] = v.z; areg[c*4+3] = v.w;
            }
        } else {
            #pragma unroll
            for (int e = 0; e < 32; ++e) {
                int pos = tbase + k0 + e;
                if (pos < 0) pos = -pos;
                else if (pos >= NSAMP) pos = 2 * NSAMP - 2 - pos;
                areg[e] = xrow[pos];
            }
        }
        const u16x8* bp = (const u16x8*)(brow + st * 64);
        #pragma unroll
        for (int c = 0; c < 4; ++c) breg[c] = bp[c];
    };

    auto write_step = [&](int buf) {
        #pragma unroll
        for (int i = 0; i < 4; ++i) {
            u16x8 v;
            #pragma unroll
            for (int e = 0; e < 8; ++e) {
                __hip_bfloat16 h = __float2bfloat16(areg[i * 8 + e]);
                v[e] = *reinterpret_cast<unsigned short*>(&h);
            }
            int off = (ar * 128 + ak * 2 + i * 16) ^ ((ar & 7) << 4);
            *(u16x8*)((char*)Al[buf] + off) = v;
        }
        #pragma unroll
        for (int i = 0; i < 4; ++i) {
            int off = (ar * 128 + ak * 2 + i * 16) ^ ((ar & 7) << 4);
            *(u16x8*)((char*)Bl[buf] + off) = breg[i];
        }
    };

    auto compute = [&](int buf) {
        #pragma unroll
        for (int kb = 0; kb < 2; ++kb) {
            const int kbyte = kb * 64 + (lane >> 4) * 16;
            bf16x8 af[4], bfr[4];
            #pragma unroll
            for (int mf = 0; mf < 4; ++mf) {
                int row = wm * 64 + mf * 16 + (lane & 15);
                int off = (row * 128 + kbyte) ^ ((row & 7) << 4);
                af[mf] = *(const bf16x8*)((const char*)Al[buf] + off);
            }
            #pragma unroll
            for (int nf = 0; nf < 4; ++nf) {
                int col = wn * 64 + nf * 16 + (lane & 15);
                int off = (col * 128 + kbyte) ^ ((col & 7) << 4);
                bfr[nf] = *(const bf16x8*)((const char*)Bl[buf] + off);
            }
            #pragma unroll
            for (int mf = 0; mf < 4; ++mf)
                #pragma unroll
                for (int nf = 0; nf < 4; ++nf)
                    acc[mf][nf] = __builtin_amdgcn_mfma_f32_16x16x32_bf16(
                        af[mf], bfr[nf], acc[mf][nf], 0, 0, 0);
        }
    };

    load_step(0);
    write_step(0);
    __syncthreads();
    for (int st = 0; st < 8; ++st) {
        if (st < 7) load_step(st + 1);     // issue next-tile global loads early
        compute(st & 1);
        __syncthreads();
        if (st < 7) write_step((st + 1) & 1);
        __syncthreads();
    }

    // epilogue: power = re^2 + im^2, re/im in adjacent 16-col fragments
    const int olane = lane & 15, qlane = lane >> 4;
    #pragma unroll
    for (int mf = 0; mf < 4; ++mf) {
        #pragma unroll
        for (int p = 0; p < 2; ++p) {
            f32x4 re = acc[mf][2 * p], im = acc[mf][2 * p + 1];
            int g2 = nt * 4 + wn * 2 + p;
            int bin = g2 * 16 + olane;
            bool nyq = (g2 == 0) && (olane == 0);   // bin0: im slot holds Nyquist
            #pragma unroll
            for (int j = 0; j < 4; ++j) {
                int R = mt * 128 + wm * 64 + mf * 16 + qlane * 4 + j;
                float pr = re[j] * re[j];
                float pi = im[j] * im[j];
                powo[(size_t)R * FPOW + bin] = nyq ? pr : (pr + pi);
                if (nyq) powo[(size_t)R * FPOW + 256] = pi;
            }
        }
    }
}

// ------------- chunked IIR scan + SPP + MSE reduction (unchanged r1) --------
__global__ __launch_bounds__(256)
void spp_loss_kernel(const float* __restrict__ noiseP,
                     const float* __restrict__ noisyP,
                     const float* __restrict__ est,
                     float* __restrict__ out,
                     float alpha)
{
    const double XI = 31.622776601683793;
    const float RATIO = (float)(1.0 + XI);
    const float COEF  = (float)(XI / (1.0 + XI));
    const float INVN  = (float)(1.0 / ((double)B_SZ * NF * T_FR));

    int tid = blockIdx.x * blockDim.x + threadIdx.x;
    int f   = tid % NF;
    int rem = tid / NF;
    int c   = rem % NCH;
    int b   = rem / NCH;

    float local = 0.f;
    if (b < B_SZ) {
        int t0   = c * CHUNK;
        int tend = min(T_FR, t0 + CHUNK);
        int ts   = max(0, t0 - WARM);
        const float* nrow = noiseP + (size_t)b * T_FR * FPOW + f;
        const float* yrow = noisyP + (size_t)b * T_FR * FPOW + f;
        const float* erow = est + ((size_t)b * NF + f) * T_FR;
        float oma = 1.f - alpha;
        float v = nrow[(size_t)ts * FPOW];
        if (ts == t0) {
            float np = yrow[(size_t)ts * FPOW];
            float expo = -np / (v + EPS_F) * COEF;
            float spp  = 1.f / fmaf(RATIO, expf(expo), 1.f);
            float d = erow[ts] - spp;
            local = fmaf(d, d, local);
        }
        for (int t = ts + 1; t < tend; ++t) {
            v = fmaf(alpha, v, oma * nrow[(size_t)t * FPOW]);
            if (t >= t0) {
                float np = yrow[(size_t)t * FPOW];
                float expo = -np / (v + EPS_F) * COEF;
                float spp  = 1.f / fmaf(RATIO, expf(expo), 1.f);
                float d = erow[t] - spp;
                local = fmaf(d, d, local);
            }
        }
    }

    for (int off = 32; off > 0; off >>= 1)
        local += __shfl_down(local, off);
    __shared__ float wsum[4];
    if ((threadIdx.x & 63) == 0) wsum[threadIdx.x >> 6] = local;
    __syncthreads();
    if (threadIdx.x == 0) {
        float ssum = (wsum[0] + wsum[1]) + (wsum[2] + wsum[3]);
        atomicAdd(out, ssum * INVN);
    }
}

extern "C" void kernel_launch(void* const* d_in, const int* in_sizes, int n_in,
                              void* d_out, int out_size, void* d_ws, size_t ws_size,
                              hipStream_t stream) {
    const float* est  = (const float*)d_in[0];   // spp_estimate (B,1,F,T)
    const float* sig  = (const float*)d_in[1];   // input_sig    (B,1,N)
    const float* intf = (const float*)d_in[2];   // interference (B,1,N)

    unsigned short* Bt = (unsigned short*)d_ws;                 // 512x512 bf16
    float* powp = (float*)((char*)d_ws + (size_t)KTOT * KTOT * 2);  // [64128][257]

    hipLaunchKernelGGL(build_basis, dim3(512), dim3(256), 0, stream, Bt);

    dim3 gG(501, 4);
    hipLaunchKernelGGL(dft_gemm, gG, dim3(256), 0, stream, sig, intf, Bt, powp);

    hipMemsetAsync(d_out, 0, sizeof(float), stream);

    const double alpha_d = exp(-((double)256) / (16000.0 * 0.072));
    const float* noiseP = powp;                          // rows 0..32063 = interference
    const float* noisyP = powp + (size_t)NFR * FPOW;     // rows 32064.. = input_sig
    dim3 gB((B_SZ * NCH * NF + 255) / 256);
    hipLaunchKernelGGL(spp_loss_kernel, gB, dim3(256), 0, stream,
                       noiseP, noisyP, est, (float*)d_out, (float)alpha_d);
}

// Round 3
// 144.934 us; speedup vs baseline: 3.1910x; 2.4625x over previous
//
#include <hip/hip_runtime.h>
#include <hip/hip_bf16.h>
#include <math.h>

typedef __attribute__((ext_vector_type(8))) short bf16x8;
typedef __attribute__((ext_vector_type(4))) float f32x4;

#define NSAMP  128000
#define TFR    501
#define NFR    32064       // 64*501 frames per signal
#define FPOW   257
#define NF     257
#define B_SZ   64
#define CHUNKT 64
#define WARM   48
#define NCH    8
#define EPS_F  1.1920928955078125e-07f

#define SEG    33024       // 128*256 + 256 samples per M-chunk segment
#define SEGB   66048       // SEG * 2 bytes (bf16)
#define BBUFB  32768       // 256 cols * 128 B per K-step tile
#define LDS_TOTAL (SEGB + 2 * BBUFB)   // 131584 B

// ---- basis, layout [st 0..7][col 0..511][k 0..63] bf16 -----------------
// col = (bin>>4)*32 + isIm*16 + (bin&15); col 16 (dead im of DC) = Nyquist.
__global__ __launch_bounds__(256)
void build_basis(unsigned short* __restrict__ Bt) {
    int col = blockIdx.x;
    int g = col >> 5, o = col & 15;
    int isIm = (col >> 4) & 1;
    int bin = g * 16 + o;
    for (int k = threadIdx.x; k < 512; k += 256) {
        float w = sinf((float)k * (float)(M_PI / 512.0));   // sqrt-hann
        float v;
        if (col == 16) {
            v = w * ((k & 1) ? -1.f : 1.f);
        } else {
            int mm = (bin * k) & 511;
            float th = (float)mm * (float)(2.0 * M_PI / 512.0);
            v = w * (isIm ? -sinf(th) : cosf(th));
        }
        __hip_bfloat16 h = __float2bfloat16(v);
        Bt[((size_t)(k >> 6) * 512 + col) * 64 + (k & 63)] =
            *reinterpret_cast<unsigned short*>(&h);
    }
}

// ---- MFMA DFT GEMM v3 ---------------------------------------------------
// grid (4 mchunk, 64 b, 2 s), block 512 (8 waves, 2M x 4N, wave tile 64x64).
// A: raw bf16 signal segment in LDS (hop-dedup), staged once, swizzled.
// B: double-buffered 256col x 64k tiles via global_load_lds (pre-swz src).
__global__ __launch_bounds__(512, 2)
void dft_gemm(const float* __restrict__ sig,
              const float* __restrict__ intf,
              const unsigned short* __restrict__ Bt,
              float* __restrict__ powo)
{
    extern __shared__ char smem[];
    char* As = smem;

    const int mchunk = blockIdx.x, b = blockIdx.y, s = blockIdx.z;
    const int tid = threadIdx.x, lane = tid & 63, wid = tid >> 6;
    const int wm = wid >> 2, wn = wid & 3;
    const float* x = (s == 0 ? intf : sig) + (size_t)b * NSAMP;
    const int tbase = mchunk * 32768 - 256;

    // ---- B staging: 4 x global_load_lds(16B) per wave = full 32KB tile ----
    const int colSub = lane >> 3;                 // 0..7
    const int bchunk = (lane & 7) ^ colSub;       // pre-swizzled source chunk
    auto stageB = [&](int q, int buf) {
        const int nt = q >> 3, st = q & 7;
        const char* gb = (const char*)Bt + ((size_t)(st * 512 + nt * 256)) * 128;
        char* lb = smem + SEGB + buf * BBUFB;
        #pragma unroll
        for (int i = 0; i < 4; ++i) {
            const char* src = gb + (size_t)(wid * 32 + i * 8 + colSub) * 128
                                 + bchunk * 16;
            char* dst = lb + (wid * 32 + i * 8) * 128;    // wave-uniform
            __builtin_amdgcn_global_load_lds(
                (const __attribute__((address_space(1))) void*)src,
                (__attribute__((address_space(3))) void*)dst, 16, 0, 0);
        }
    };

    stageB(0, 0);   // in flight during A staging

    // ---- A staging: contiguous segment, float4, bf16, addr-XOR swizzle ----
    {
        const int jlo = (tbase < 0) ? -tbase : 0;                  // 256 or 0
        const int jhi = (tbase + SEG > NSAMP) ? (NSAMP - tbase) : SEG;
        for (int i = tid; i < SEG / 4; i += 512) {
            int j = i * 4;
            float f0, f1, f2, f3;
            if (j >= jlo && j + 4 <= jhi) {
                float4 v = *(const float4*)(x + tbase + j);
                f0 = v.x; f1 = v.y; f2 = v.z; f3 = v.w;
            } else {
                int p0 = tbase + j;
                int pp[4];
                #pragma unroll
                for (int e = 0; e < 4; ++e) {
                    int p = p0 + e;
                    if (p < 0) p = -p;
                    if (p >= NSAMP) p = 2 * NSAMP - 2 - p;
                    pp[e] = p;
                }
                f0 = x[pp[0]]; f1 = x[pp[1]]; f2 = x[pp[2]]; f3 = x[pp[3]];
            }
            unsigned short h[4];
            __hip_bfloat16 t0 = __float2bfloat16(f0); h[0] = *(unsigned short*)&t0;
            __hip_bfloat16 t1 = __float2bfloat16(f1); h[1] = *(unsigned short*)&t1;
            __hip_bfloat16 t2 = __float2bfloat16(f2); h[2] = *(unsigned short*)&t2;
            __hip_bfloat16 t3 = __float2bfloat16(f3); h[3] = *(unsigned short*)&t3;
            unsigned long long pk =
                (unsigned long long)h[0] | ((unsigned long long)h[1] << 16) |
                ((unsigned long long)h[2] << 32) | ((unsigned long long)h[3] << 48);
            int a = i * 8;
            a ^= ((a >> 9) & 7) << 4;
            *(unsigned long long*)(As + a) = pk;
        }
    }
    asm volatile("s_waitcnt vmcnt(0)" ::: "memory");
    __syncthreads();

    f32x4 acc[4][4];
    #pragma unroll
    for (int i = 0; i < 4; ++i)
        #pragma unroll
        for (int j = 0; j < 4; ++j) acc[i][j] = 0;

    const size_t rowbase = ((size_t)(s * 64 + b)) * TFR;
    const int olane = lane & 15, qlane = lane >> 4;

    for (int q = 0; q < 16; ++q) {
        const char* bufp = smem + SEGB + (q & 1) * BBUFB;
        if (q < 15) stageB(q + 1, (q + 1) & 1);

        const int st = q & 7;
        #pragma unroll
        for (int kb = 0; kb < 2; ++kb) {
            const int ko = kb * 64 + (lane >> 4) * 16;
            bf16x8 af[4], bfr[4];
            #pragma unroll
            for (int mf = 0; mf < 4; ++mf) {
                int row = wm * 64 + mf * 16 + (lane & 15);
                int a = row * 512 + st * 128 + ko;
                a ^= ((a >> 9) & 7) << 4;
                af[mf] = *(const bf16x8*)(As + a);
            }
            #pragma unroll
            for (int nf = 0; nf < 4; ++nf) {
                int col = wn * 64 + nf * 16 + (lane & 15);
                int bo = col * 128 + ko;
                bo ^= ((bo >> 7) & 7) << 4;
                bfr[nf] = *(const bf16x8*)(bufp + bo);
            }
            #pragma unroll
            for (int mf = 0; mf < 4; ++mf)
                #pragma unroll
                for (int nf = 0; nf < 4; ++nf)
                    acc[mf][nf] = __builtin_amdgcn_mfma_f32_16x16x32_bf16(
                        af[mf], bfr[nf], acc[mf][nf], 0, 0, 0);
        }

        asm volatile("s_waitcnt vmcnt(0)" ::: "memory");
        __syncthreads();

        if (st == 7) {
            // ---- epilogue for this nt: power = re^2 + im^2 ----
            const int nt = q >> 3;
            #pragma unroll
            for (int mf = 0; mf < 4; ++mf) {
                #pragma unroll
                for (int p = 0; p < 2; ++p) {
                    f32x4 re = acc[mf][2 * p], im = acc[mf][2 * p + 1];
                    int g2 = nt * 8 + wn * 2 + p;
                    int bin = g2 * 16 + olane;
                    bool nyq = (g2 == 0) && (olane == 0);
                    #pragma unroll
                    for (int j = 0; j < 4; ++j) {
                        int rl = mchunk * 128 + wm * 64 + mf * 16 + qlane * 4 + j;
                        if (rl < TFR) {
                            float pr = re[j] * re[j];
                            float pi = im[j] * im[j];
                            float* po = powo + (rowbase + rl) * FPOW;
                            po[bin] = nyq ? pr : (pr + pi);
                            if (nyq) po[256] = pi;
                        }
                    }
                }
            }
            #pragma unroll
            for (int i = 0; i < 4; ++i)
                #pragma unroll
                for (int j = 0; j < 4; ++j) acc[i][j] = 0;
        }
    }
}

// ------------- chunked IIR scan + SPP + MSE reduction --------------------
__global__ __launch_bounds__(256)
void spp_loss_kernel(const float* __restrict__ noiseP,
                     const float* __restrict__ noisyP,
                     const float* __restrict__ est,
                     float* __restrict__ out,
                     float alpha)
{
    const double XI = 31.622776601683793;
    const float RATIO = (float)(1.0 + XI);
    const float COEF  = (float)(XI / (1.0 + XI));
    const float INVN  = (float)(1.0 / ((double)B_SZ * NF * TFR));

    int tid = blockIdx.x * blockDim.x + threadIdx.x;
    int f   = tid % NF;
    int rem = tid / NF;
    int c   = rem % NCH;
    int b   = rem / NCH;

    float local = 0.f;
    if (b < B_SZ) {
        int t0   = c * CHUNKT;
        int tend = min(TFR, t0 + CHUNKT);
        int ts   = max(0, t0 - WARM);
        const float* nrow = noiseP + (size_t)b * TFR * FPOW + f;
        const float* yrow = noisyP + (size_t)b * TFR * FPOW + f;
        const float* erow = est + ((size_t)b * NF + f) * TFR;
        float oma = 1.f - alpha;
        float v = nrow[(size_t)ts * FPOW];
        if (ts == t0) {
            float np = yrow[(size_t)ts * FPOW];
            float expo = -np / (v + EPS_F) * COEF;
            float spp  = 1.f / fmaf(RATIO, expf(expo), 1.f);
            float d = erow[ts] - spp;
            local = fmaf(d, d, local);
        }
        for (int t = ts + 1; t < tend; ++t) {
            v = fmaf(alpha, v, oma * nrow[(size_t)t * FPOW]);
            if (t >= t0) {
                float np = yrow[(size_t)t * FPOW];
                float expo = -np / (v + EPS_F) * COEF;
                float spp  = 1.f / fmaf(RATIO, expf(expo), 1.f);
                float d = erow[t] - spp;
                local = fmaf(d, d, local);
            }
        }
    }

    for (int off = 32; off > 0; off >>= 1)
        local += __shfl_down(local, off);
    __shared__ float wsum[4];
    if ((threadIdx.x & 63) == 0) wsum[threadIdx.x >> 6] = local;
    __syncthreads();
    if (threadIdx.x == 0) {
        float ssum = (wsum[0] + wsum[1]) + (wsum[2] + wsum[3]);
        atomicAdd(out, ssum * INVN);
    }
}

extern "C" void kernel_launch(void* const* d_in, const int* in_sizes, int n_in,
                              void* d_out, int out_size, void* d_ws, size_t ws_size,
                              hipStream_t stream) {
    const float* est  = (const float*)d_in[0];   // spp_estimate (B,1,F,T)
    const float* sig  = (const float*)d_in[1];   // input_sig    (B,1,N)
    const float* intf = (const float*)d_in[2];   // interference (B,1,N)

    unsigned short* Bt = (unsigned short*)d_ws;                 // 512 KB basis
    float* powp = (float*)((char*)d_ws + (size_t)8 * 512 * 64 * 2);

    hipLaunchKernelGGL(build_basis, dim3(512), dim3(256), 0, stream, Bt);

    hipFuncSetAttribute((const void*)dft_gemm,
                        hipFuncAttributeMaxDynamicSharedMemorySize, LDS_TOTAL);
    dim3 gG(4, 64, 2);
    hipLaunchKernelGGL(dft_gemm, gG, dim3(512), LDS_TOTAL, stream,
                       sig, intf, Bt, powp);

    hipMemsetAsync(d_out, 0, sizeof(float), stream);

    const double alpha_d = exp(-((double)256) / (16000.0 * 0.072));
    const float* noiseP = powp;                          // s=0: interference
    const float* noisyP = powp + (size_t)NFR * FPOW;     // s=1: input_sig
    dim3 gB((B_SZ * NCH * NF + 255) / 256);
    hipLaunchKernelGGL(spp_loss_kernel, gB, dim3(256), 0, stream,
                       noiseP, noisyP, est, (float*)d_out, (float)alpha_d);
}

// Round 4
// 109.791 us; speedup vs baseline: 4.2125x; 1.3201x over previous
//
#include <hip/hip_runtime.h>
#include <hip/hip_bf16.h>
#include <math.h>

typedef __attribute__((ext_vector_type(8))) short bf16x8;
typedef __attribute__((ext_vector_type(4))) float f32x4;

#define NSAMP  128000
#define TFR    501
#define NFR    32064       // 64*501 frames per signal
#define FPOW   257
#define NF     257
#define B_SZ   64
#define CHUNKT 32
#define NCH    16
#define EPS_F  1.1920928955078125e-07f

#define SEG    33024       // 128*256 + 256 samples per M-chunk segment
#define SEGB   66048       // SEG * 2 bytes (bf16)
#define BBUFB  32768       // 256 cols * 128 B per K-step tile
#define LDS_TOTAL (SEGB + 2 * BBUFB)   // 131584 B

// ---- basis, layout [st 0..7][col 0..511][k 0..63] bf16 -----------------
// col = (bin>>4)*32 + isIm*16 + (bin&15); col 16 (dead im of DC) = Nyquist.
__global__ __launch_bounds__(256)
void build_basis(unsigned short* __restrict__ Bt) {
    int col = blockIdx.x;
    int g = col >> 5, o = col & 15;
    int isIm = (col >> 4) & 1;
    int bin = g * 16 + o;
    for (int k = threadIdx.x; k < 512; k += 256) {
        float w = sinf((float)k * (float)(M_PI / 512.0));   // sqrt-hann
        float v;
        if (col == 16) {
            v = w * ((k & 1) ? -1.f : 1.f);
        } else {
            int mm = (bin * k) & 511;
            float th = (float)mm * (float)(2.0 * M_PI / 512.0);
            v = w * (isIm ? -sinf(th) : cosf(th));
        }
        __hip_bfloat16 h = __float2bfloat16(v);
        Bt[((size_t)(k >> 6) * 512 + col) * 64 + (k & 63)] =
            *reinterpret_cast<unsigned short*>(&h);
    }
}

// ---- MFMA DFT GEMM (unchanged from r3) ---------------------------------
__global__ __launch_bounds__(512, 2)
void dft_gemm(const float* __restrict__ sig,
              const float* __restrict__ intf,
              const unsigned short* __restrict__ Bt,
              float* __restrict__ powo)
{
    extern __shared__ char smem[];
    char* As = smem;

    const int mchunk = blockIdx.x, b = blockIdx.y, s = blockIdx.z;
    const int tid = threadIdx.x, lane = tid & 63, wid = tid >> 6;
    const int wm = wid >> 2, wn = wid & 3;
    const float* x = (s == 0 ? intf : sig) + (size_t)b * NSAMP;
    const int tbase = mchunk * 32768 - 256;

    const int colSub = lane >> 3;
    const int bchunk = (lane & 7) ^ colSub;
    auto stageB = [&](int q, int buf) {
        const int nt = q >> 3, st = q & 7;
        const char* gb = (const char*)Bt + ((size_t)(st * 512 + nt * 256)) * 128;
        char* lb = smem + SEGB + buf * BBUFB;
        #pragma unroll
        for (int i = 0; i < 4; ++i) {
            const char* src = gb + (size_t)(wid * 32 + i * 8 + colSub) * 128
                                 + bchunk * 16;
            char* dst = lb + (wid * 32 + i * 8) * 128;
            __builtin_amdgcn_global_load_lds(
                (const __attribute__((address_space(1))) void*)src,
                (__attribute__((address_space(3))) void*)dst, 16, 0, 0);
        }
    };

    stageB(0, 0);

    {
        const int jlo = (tbase < 0) ? -tbase : 0;
        const int jhi = (tbase + SEG > NSAMP) ? (NSAMP - tbase) : SEG;
        for (int i = tid; i < SEG / 4; i += 512) {
            int j = i * 4;
            float f0, f1, f2, f3;
            if (j >= jlo && j + 4 <= jhi) {
                float4 v = *(const float4*)(x + tbase + j);
                f0 = v.x; f1 = v.y; f2 = v.z; f3 = v.w;
            } else {
                int p0 = tbase + j;
                int pp[4];
                #pragma unroll
                for (int e = 0; e < 4; ++e) {
                    int p = p0 + e;
                    if (p < 0) p = -p;
                    if (p >= NSAMP) p = 2 * NSAMP - 2 - p;
                    pp[e] = p;
                }
                f0 = x[pp[0]]; f1 = x[pp[1]]; f2 = x[pp[2]]; f3 = x[pp[3]];
            }
            unsigned short h[4];
            __hip_bfloat16 t0 = __float2bfloat16(f0); h[0] = *(unsigned short*)&t0;
            __hip_bfloat16 t1 = __float2bfloat16(f1); h[1] = *(unsigned short*)&t1;
            __hip_bfloat16 t2 = __float2bfloat16(f2); h[2] = *(unsigned short*)&t2;
            __hip_bfloat16 t3 = __float2bfloat16(f3); h[3] = *(unsigned short*)&t3;
            unsigned long long pk =
                (unsigned long long)h[0] | ((unsigned long long)h[1] << 16) |
                ((unsigned long long)h[2] << 32) | ((unsigned long long)h[3] << 48);
            int a = i * 8;
            a ^= ((a >> 9) & 7) << 4;
            *(unsigned long long*)(As + a) = pk;
        }
    }
    asm volatile("s_waitcnt vmcnt(0)" ::: "memory");
    __syncthreads();

    f32x4 acc[4][4];
    #pragma unroll
    for (int i = 0; i < 4; ++i)
        #pragma unroll
        for (int j = 0; j < 4; ++j) acc[i][j] = 0;

    const size_t rowbase = ((size_t)(s * 64 + b)) * TFR;
    const int olane = lane & 15, qlane = lane >> 4;

    for (int q = 0; q < 16; ++q) {
        const char* bufp = smem + SEGB + (q & 1) * BBUFB;
        if (q < 15) stageB(q + 1, (q + 1) & 1);

        const int st = q & 7;
        #pragma unroll
        for (int kb = 0; kb < 2; ++kb) {
            const int ko = kb * 64 + (lane >> 4) * 16;
            bf16x8 af[4], bfr[4];
            #pragma unroll
            for (int mf = 0; mf < 4; ++mf) {
                int row = wm * 64 + mf * 16 + (lane & 15);
                int a = row * 512 + st * 128 + ko;
                a ^= ((a >> 9) & 7) << 4;
                af[mf] = *(const bf16x8*)(As + a);
            }
            #pragma unroll
            for (int nf = 0; nf < 4; ++nf) {
                int col = wn * 64 + nf * 16 + (lane & 15);
                int bo = col * 128 + ko;
                bo ^= ((bo >> 7) & 7) << 4;
                bfr[nf] = *(const bf16x8*)(bufp + bo);
            }
            #pragma unroll
            for (int mf = 0; mf < 4; ++mf)
                #pragma unroll
                for (int nf = 0; nf < 4; ++nf)
                    acc[mf][nf] = __builtin_amdgcn_mfma_f32_16x16x32_bf16(
                        af[mf], bfr[nf], acc[mf][nf], 0, 0, 0);
        }

        asm volatile("s_waitcnt vmcnt(0)" ::: "memory");
        __syncthreads();

        if (st == 7) {
            const int nt = q >> 3;
            #pragma unroll
            for (int mf = 0; mf < 4; ++mf) {
                #pragma unroll
                for (int p = 0; p < 2; ++p) {
                    f32x4 re = acc[mf][2 * p], im = acc[mf][2 * p + 1];
                    int g2 = nt * 8 + wn * 2 + p;
                    int bin = g2 * 16 + olane;
                    bool nyq = (g2 == 0) && (olane == 0);
                    #pragma unroll
                    for (int j = 0; j < 4; ++j) {
                        int rl = mchunk * 128 + wm * 64 + mf * 16 + qlane * 4 + j;
                        if (rl < TFR) {
                            float pr = re[j] * re[j];
                            float pi = im[j] * im[j];
                            float* po = powo + (rowbase + rl) * FPOW;
                            po[bin] = nyq ? pr : (pr + pi);
                            if (nyq) po[256] = pi;
                        }
                    }
                }
            }
            #pragma unroll
            for (int i = 0; i < 4; ++i)
                #pragma unroll
                for (int j = 0; j < 4; ++j) acc[i][j] = 0;
        }
    }
}

// ---- warm-up: batched loads then fmaf chain -----------------------------
template<int W>
__device__ __forceinline__ float warm_sum(const float* __restrict__ nrow,
                                          int ts, float alpha, float oma) {
    float q[W + 1];
    #pragma unroll
    for (int i = 0; i <= W; ++i) q[i] = nrow[(size_t)(ts + i) * FPOW];
    float v = q[0];
    #pragma unroll
    for (int i = 1; i <= W; ++i) v = fmaf(alpha, v, oma * q[i]);
    return v;
}

// ---- chunked IIR scan + SPP + MSE, pipelined & unrolled ----------------
__global__ __launch_bounds__(256, 4)
void spp_loss_kernel(const float* __restrict__ noiseP,
                     const float* __restrict__ noisyP,
                     const float* __restrict__ est,
                     float* __restrict__ out,
                     float alpha)
{
    const double XI = 31.622776601683793;
    const float RATIO = (float)(1.0 + XI);
    const float COEF  = (float)(XI / (1.0 + XI));
    const float INVN  = (float)(1.0 / ((double)B_SZ * NF * TFR));

    int tid = blockIdx.x * blockDim.x + threadIdx.x;
    int f   = tid % NF;
    int rem = tid / NF;
    int c   = rem & (NCH - 1);
    int b   = rem >> 4;

    float local = 0.f;
    if (b < B_SZ) {
        const int t0   = c * CHUNKT;
        const int tend = min(TFR, t0 + CHUNKT);
        const float* nrow = noiseP + (size_t)b * TFR * FPOW + f;
        const float* yrow = noisyP + (size_t)b * TFR * FPOW + f;
        const float* erow = est + ((size_t)b * NF + f) * TFR;
        const float oma = 1.f - alpha;

        float v;
        if (t0 == 0)            v = nrow[0];
        else if (t0 == CHUNKT)  v = warm_sum<CHUNKT>(nrow, 0, alpha, oma);
        else                    v = warm_sum<48>(nrow, t0 - 48, alpha, oma);

        // emit at t0
        {
            float np = yrow[(size_t)t0 * FPOW];
            float e0 = erow[t0];
            float expo = -np / (v + EPS_F) * COEF;
            float spp  = 1.f / fmaf(RATIO, __expf(expo), 1.f);
            float d = e0 - spp;
            local = fmaf(d, d, local);
        }
        // emit t0+1 .. tend-1 in two batched halves of 16
        #pragma unroll
        for (int h = 0; h < 2; ++h) {
            float qn[16], qy[16], qe[16];
            #pragma unroll
            for (int i = 0; i < 16; ++i) {
                int t = min(t0 + h * 16 + i + 1, TFR - 1);
                qn[i] = nrow[(size_t)t * FPOW];
                qy[i] = yrow[(size_t)t * FPOW];
                qe[i] = erow[t];
            }
            #pragma unroll
            for (int i = 0; i < 16; ++i) {
                int t = t0 + h * 16 + i + 1;
                v = fmaf(alpha, v, oma * qn[i]);
                if (t < tend) {
                    float expo = -qy[i] / (v + EPS_F) * COEF;
                    float spp  = 1.f / fmaf(RATIO, __expf(expo), 1.f);
                    float d = qe[i] - spp;
                    local = fmaf(d, d, local);
                }
            }
        }
    }

    for (int off = 32; off > 0; off >>= 1)
        local += __shfl_down(local, off);
    __shared__ float wsum[4];
    if ((threadIdx.x & 63) == 0) wsum[threadIdx.x >> 6] = local;
    __syncthreads();
    if (threadIdx.x == 0) {
        float ssum = (wsum[0] + wsum[1]) + (wsum[2] + wsum[3]);
        atomicAdd(out, ssum * INVN);
    }
}

extern "C" void kernel_launch(void* const* d_in, const int* in_sizes, int n_in,
                              void* d_out, int out_size, void* d_ws, size_t ws_size,
                              hipStream_t stream) {
    const float* est  = (const float*)d_in[0];   // spp_estimate (B,1,F,T)
    const float* sig  = (const float*)d_in[1];   // input_sig    (B,1,N)
    const float* intf = (const float*)d_in[2];   // interference (B,1,N)

    unsigned short* Bt = (unsigned short*)d_ws;                 // 512 KB basis
    float* powp = (float*)((char*)d_ws + (size_t)8 * 512 * 64 * 2);

    hipLaunchKernelGGL(build_basis, dim3(512), dim3(256), 0, stream, Bt);
    hipMemsetAsync(d_out, 0, sizeof(float), stream);

    hipFuncSetAttribute((const void*)dft_gemm,
                        hipFuncAttributeMaxDynamicSharedMemorySize, LDS_TOTAL);
    dim3 gG(4, 64, 2);
    hipLaunchKernelGGL(dft_gemm, gG, dim3(512), LDS_TOTAL, stream,
                       sig, intf, Bt, powp);

    const double alpha_d = exp(-((double)256) / (16000.0 * 0.072));
    const float* noiseP = powp;                          // s=0: interference
    const float* noisyP = powp + (size_t)NFR * FPOW;     // s=1: input_sig
    dim3 gB((B_SZ * NCH * NF + 255) / 256);
    hipLaunchKernelGGL(spp_loss_kernel, gB, dim3(256), 0, stream,
                       noiseP, noisyP, est, (float*)d_out, (float)alpha_d);
}